// Round 2
// baseline (231.343 us; speedup 1.0000x reference)
//
#include <hip/hip_runtime.h>

#define CAM_FL 540.0f
#define CAM_W  640
#define CAM_H  480
#define RADIUS 2
#define KSIZE  (2 * RADIUS + 1)   // 5
#define TAPS   (KSIZE * KSIZE)    // 25

// ---------------------------------------------------------------------------
// Kernel 1: project + cull + compact.
// One thread per particle, blockIdx.y = batch. Survivors append a float4
// record {px, py, z, batch} to the workspace. The counter atomicAdd is
// wave-aggregated by the compiler (one global atomic + mbcnt per wave).
// ---------------------------------------------------------------------------
__global__ __launch_bounds__(256) void project_cull_kernel(
    const float* __restrict__ locs,        // [B, N, 3]
    const float* __restrict__ camera_pose, // [B, 3]
    const float* __restrict__ camera_rot,  // [B, 4]
    float4* __restrict__ surv,             // [cap] survivor records
    int* __restrict__ counter,             // [1]
    int N, int cap)
{
#pragma clang fp contract(off)
    const int b = blockIdx.y;
    const int n = blockIdx.x * blockDim.x + threadIdx.x;
    if (n >= N) return;

    // --- camera params (uniform within block) ---
    const float qx_raw = camera_rot[b * 4 + 0];
    const float qy_raw = camera_rot[b * 4 + 1];
    const float qz_raw = camera_rot[b * 4 + 2];
    const float qw_raw = camera_rot[b * 4 + 3];
    const float norm2 = ((qx_raw * qx_raw + qy_raw * qy_raw) + qz_raw * qz_raw) + qw_raw * qw_raw;
    const float s = sqrtf(norm2);
    const float qx = -(qx_raw / s);
    const float qy = -(qy_raw / s);
    const float qz = -(qz_raw / s);
    const float qw =  (qw_raw / s);

    const float qx2 = qx * qx, qy2 = qy * qy, qz2 = qz * qz;
    const float qxqy = qx * qy, qxqz = qx * qz, qxqw = qx * qw;
    const float qyqz = qy * qz, qyqw = qy * qw, qzqw = qz * qw;
    const float r00 = (1.0f - 2.0f * qy2) - 2.0f * qz2;
    const float r10 = 2.0f * qxqy - 2.0f * qzqw;
    const float r20 = 2.0f * qxqz + 2.0f * qyqw;
    const float r01 = 2.0f * qxqy + 2.0f * qzqw;
    const float r11 = (1.0f - 2.0f * qx2) - 2.0f * qz2;
    const float r21 = 2.0f * qyqz - 2.0f * qxqw;
    const float r02 = 2.0f * qxqz - 2.0f * qyqw;
    const float r12 = 2.0f * qyqz + 2.0f * qxqw;
    const float r22 = (1.0f - 2.0f * qx2) - 2.0f * qy2;

    const float cpx = camera_pose[b * 3 + 0];
    const float cpy = camera_pose[b * 3 + 1];
    const float cpz = camera_pose[b * 3 + 2];

    const float p0 = locs[(size_t)(b * N + n) * 3 + 0] - cpx;
    const float p1 = locs[(size_t)(b * N + n) * 3 + 1] - cpy;
    const float p2 = locs[(size_t)(b * N + n) * 3 + 2] - cpz;

    // p' = p . R, association order matches reference ((a+b)+c)
    const float x = (p0 * r00 + p1 * r10) + p2 * r20;
    const float y = (p0 * r01 + p1 * r11) + p2 * r21;
    const float z = (p0 * r02 + p1 * r12) + p2 * r22;

    if (!(z > 0.0f)) return;

    const float px = (x / z) * CAM_FL + (float)CAM_W * 0.5f;
    const float py = (y / z) * CAM_FL + (float)CAM_H * 0.5f;

    // frustum cull in float domain BEFORE int conversion (avoids f->i overflow
    // for Cauchy-tail projections). Stamp intersects image iff
    // floor(px) in [-RADIUS, W-1+RADIUS] and floor(py) in [-RADIUS, H-1+RADIUS].
    if (!(px >= -(float)RADIUS && px < (float)(CAM_W + RADIUS) &&
          py >= -(float)RADIUS && py < (float)(CAM_H + RADIUS)))
        return;

    const int idx = atomicAdd(counter, 1);   // wave-aggregated by compiler
    if (idx < cap)
        surv[idx] = make_float4(px, py, z, __int_as_float(b));
}

// ---------------------------------------------------------------------------
// Kernel 2: tap-level splat over the compacted survivor list.
// Work item = (survivor, tap). 25 consecutive lanes share one survivor
// record; taps map to adjacent pixels (coalesced depth gathers / atomics).
// ---------------------------------------------------------------------------
__global__ __launch_bounds__(256) void splat_kernel(
    const float4* __restrict__ surv,
    const int* __restrict__ counter,
    const float* __restrict__ depth,       // [B, H, W]
    float* __restrict__ out,               // [B, H, W]
    int cap)
{
#pragma clang fp contract(off)
    const int count = min(*counter, cap);
    const int total = count * TAPS;
    const int stride = gridDim.x * blockDim.x;

    for (int idx = blockIdx.x * blockDim.x + threadIdx.x; idx < total; idx += stride) {
        const int si  = idx / TAPS;          // magic-mul constant division
        const int tap = idx - si * TAPS;
        const int ti  = tap / KSIZE;         // 0..4 row of stamp
        const int tj  = tap - ti * KSIZE;    // 0..4 col of stamp

        const float4 r = surv[si];
        const float px = r.x;
        const float py = r.y;
        const float z  = r.z;
        const int   b  = __float_as_int(r.w);

        const int iy = (int)floorf(py) + ti - RADIUS;
        const int jx = (int)floorf(px) + tj - RADIUS;
        if ((unsigned)iy >= (unsigned)CAM_H || (unsigned)jx >= (unsigned)CAM_W)
            continue;

        const size_t pix = (size_t)b * (CAM_H * CAM_W) + (size_t)iy * CAM_W + jx;
        const float d = depth[pix];
        if (z <= d) {
            const float dyf = (float)iy - py;
            const float dxf = (float)jx - px;
            const float w = expf(-(dyf * dyf + dxf * dxf) * 0.5f);
            atomicAdd(&out[pix], w);
        }
    }
}

extern "C" void kernel_launch(void* const* d_in, const int* in_sizes, int n_in,
                              void* d_out, int out_size, void* d_ws, size_t ws_size,
                              hipStream_t stream) {
    const float* locs        = (const float*)d_in[0];
    const float* camera_pose = (const float*)d_in[1];
    const float* camera_rot  = (const float*)d_in[2];
    const float* depth_mask  = (const float*)d_in[3];
    float* out = (float*)d_out;

    const int B = in_sizes[1] / 3;             // camera_pose is [B,3]
    const int N = in_sizes[0] / (3 * B);       // locs is [B,N,3]

    // workspace layout: [0..15] counter (only first 4 bytes used),
    //                   [16..]  float4 survivor records
    int* counter = (int*)d_ws;
    float4* surv = (float4*)((char*)d_ws + 16);
    const int cap = (int)((ws_size - 16) / sizeof(float4));

    hipMemsetAsync(d_out, 0, (size_t)out_size * sizeof(float), stream);
    hipMemsetAsync(d_ws, 0, 16, stream);

    dim3 block(256, 1, 1);
    dim3 grid1((N + 255) / 256, B, 1);
    project_cull_kernel<<<grid1, block, 0, stream>>>(
        locs, camera_pose, camera_rot, surv, counter, N, cap);

    // grid-stride: 2048 blocks x 256 = 524288 resident work items
    splat_kernel<<<dim3(2048, 1, 1), block, 0, stream>>>(
        surv, counter, depth_mask, out, cap);
}

// Round 3
// 87.786 us; speedup vs baseline: 2.6353x; 2.6353x over previous
//
#include <hip/hip_runtime.h>

#define CAM_FL 540.0f
#define CAM_W  640
#define CAM_H  480
#define RADIUS 2
#define KSIZE  (2 * RADIUS + 1)   // 5
#define TAPS   (KSIZE * KSIZE)    // 25
#define BLK    256

// Single kernel: project -> block-local LDS compaction -> tap-parallel splat.
// No global counters (round 2 lesson: same-address global atomics serialize
// at ~28 cyc/op in L2 -> 145us for 12.5k ops). Control flow is block-local.
__global__ __launch_bounds__(BLK) void particle_project_kernel(
    const float* __restrict__ locs,        // [B, N, 3]
    const float* __restrict__ camera_pose, // [B, 3]
    const float* __restrict__ camera_rot,  // [B, 4]
    const float* __restrict__ depth,       // [B, H, W]
    float* __restrict__ out,               // [B, H, W]
    int N)
{
#pragma clang fp contract(off)
    __shared__ float s_px[BLK];
    __shared__ float s_py[BLK];
    __shared__ float s_z[BLK];
    __shared__ int   s_cnt;

    const int b   = blockIdx.y;
    const int n   = blockIdx.x * blockDim.x + threadIdx.x;
    const int tid = threadIdx.x;

    if (tid == 0) s_cnt = 0;

    // --- camera params (uniform within block) ---
    const float qx_raw = camera_rot[b * 4 + 0];
    const float qy_raw = camera_rot[b * 4 + 1];
    const float qz_raw = camera_rot[b * 4 + 2];
    const float qw_raw = camera_rot[b * 4 + 3];
    const float norm2 = ((qx_raw * qx_raw + qy_raw * qy_raw) + qz_raw * qz_raw) + qw_raw * qw_raw;
    const float s = sqrtf(norm2);
    const float qx = -(qx_raw / s);
    const float qy = -(qy_raw / s);
    const float qz = -(qz_raw / s);
    const float qw =  (qw_raw / s);

    const float qx2 = qx * qx, qy2 = qy * qy, qz2 = qz * qz;
    const float qxqy = qx * qy, qxqz = qx * qz, qxqw = qx * qw;
    const float qyqz = qy * qz, qyqw = qy * qw, qzqw = qz * qw;
    const float r00 = (1.0f - 2.0f * qy2) - 2.0f * qz2;
    const float r10 = 2.0f * qxqy - 2.0f * qzqw;
    const float r20 = 2.0f * qxqz + 2.0f * qyqw;
    const float r01 = 2.0f * qxqy + 2.0f * qzqw;
    const float r11 = (1.0f - 2.0f * qx2) - 2.0f * qz2;
    const float r21 = 2.0f * qyqz - 2.0f * qxqw;
    const float r02 = 2.0f * qxqz - 2.0f * qyqw;
    const float r12 = 2.0f * qyqz + 2.0f * qxqw;
    const float r22 = (1.0f - 2.0f * qx2) - 2.0f * qy2;

    const float cpx = camera_pose[b * 3 + 0];
    const float cpy = camera_pose[b * 3 + 1];
    const float cpz = camera_pose[b * 3 + 2];

    // --- projection (guarded loads; no early return before barriers) ---
    bool alive = (n < N);
    float px = 0.0f, py = 0.0f, z = 0.0f;
    if (alive) {
        const float p0 = locs[(size_t)(b * N + n) * 3 + 0] - cpx;
        const float p1 = locs[(size_t)(b * N + n) * 3 + 1] - cpy;
        const float p2 = locs[(size_t)(b * N + n) * 3 + 2] - cpz;

        // p' = p . R, association order matches reference ((a+b)+c)
        const float x = (p0 * r00 + p1 * r10) + p2 * r20;
        const float y = (p0 * r01 + p1 * r11) + p2 * r21;
        z             = (p0 * r02 + p1 * r12) + p2 * r22;

        alive = (z > 0.0f);
        if (alive) {
            px = (x / z) * CAM_FL + (float)CAM_W * 0.5f;
            py = (y / z) * CAM_FL + (float)CAM_H * 0.5f;
            // float-domain frustum cull before any int conversion
            alive = (px >= -(float)RADIUS && px < (float)(CAM_W + RADIUS) &&
                     py >= -(float)RADIUS && py < (float)(CAM_H + RADIUS));
        }
    }

    __syncthreads();   // s_cnt = 0 visible

    // --- block-local compaction: ballot + rank + one LDS atomic per wave ---
    const unsigned long long mask = __ballot(alive);
    const int lane   = tid & 63;
    const int rank   = __popcll(mask & ((1ull << lane) - 1ull));
    const int wcount = __popcll(mask);

    int wbase_v = 0;
    if (lane == 0 && wcount > 0) wbase_v = atomicAdd(&s_cnt, wcount);
    const int wbase = __shfl(wbase_v, 0);

    if (alive) {
        const int i = wbase + rank;
        s_px[i] = px;
        s_py[i] = py;
        s_z[i]  = z;
    }

    __syncthreads();

    // --- tap-parallel splat over the block's survivors ---
    const int ns    = s_cnt;
    const int total = ns * TAPS;
    const float* depth_b = depth + (size_t)b * (CAM_H * CAM_W);
    float*       out_b   = out   + (size_t)b * (CAM_H * CAM_W);

    for (int t = tid; t < total; t += BLK) {
        const int si  = t / TAPS;            // magic-mul const division
        const int tap = t - si * TAPS;
        const int ti  = tap / KSIZE;
        const int tj  = tap - ti * KSIZE;

        // 25 consecutive lanes read the same record -> LDS broadcast, free
        const float spx = s_px[si];
        const float spy = s_py[si];
        const float sz  = s_z[si];

        const int iy = (int)floorf(spy) + ti - RADIUS;
        const int jx = (int)floorf(spx) + tj - RADIUS;
        if ((unsigned)iy >= (unsigned)CAM_H || (unsigned)jx >= (unsigned)CAM_W)
            continue;

        const int pix = iy * CAM_W + jx;
        const float d = depth_b[pix];
        if (sz <= d) {
            const float dyf = (float)iy - spy;
            const float dxf = (float)jx - spx;
            const float w = expf(-(dyf * dyf + dxf * dxf) * 0.5f);
            atomicAdd(&out_b[pix], w);
        }
    }
}

extern "C" void kernel_launch(void* const* d_in, const int* in_sizes, int n_in,
                              void* d_out, int out_size, void* d_ws, size_t ws_size,
                              hipStream_t stream) {
    const float* locs        = (const float*)d_in[0];
    const float* camera_pose = (const float*)d_in[1];
    const float* camera_rot  = (const float*)d_in[2];
    const float* depth_mask  = (const float*)d_in[3];
    float* out = (float*)d_out;

    const int B = in_sizes[1] / 3;             // camera_pose is [B,3]
    const int N = in_sizes[0] / (3 * B);       // locs is [B,N,3]

    // harness poisons d_out with 0xAA before every timed launch
    hipMemsetAsync(d_out, 0, (size_t)out_size * sizeof(float), stream);

    dim3 block(BLK, 1, 1);
    dim3 grid((N + BLK - 1) / BLK, B, 1);
    particle_project_kernel<<<grid, block, 0, stream>>>(
        locs, camera_pose, camera_rot, depth_mask, out, N);
}

// Round 4
// 86.890 us; speedup vs baseline: 2.6625x; 1.0103x over previous
//
#include <hip/hip_runtime.h>

#define CAM_FL 540.0f
#define CAM_W  640
#define CAM_H  480
#define RADIUS 2
#define KSIZE  (2 * RADIUS + 1)   // 5
#define TAPS   (KSIZE * KSIZE)    // 25
#define BLK    256

// Single kernel: project -> block-local LDS compaction (with per-survivor
// separable-Gaussian precompute) -> tap-parallel splat.
// R2 lesson: no global counters (same-address global atomics ~28 cyc/op).
// R4: w = exp(-(dy^2+dx^2)/2) = exp(-dy^2/2)*exp(-dx^2/2); the 5 row and
// 5 col weights are computed ONCE per survivor (10 exps) instead of one
// fused exp per tap (25 exps), and the tap loop becomes mul+gather+atomic.
__global__ __launch_bounds__(BLK) void particle_project_kernel(
    const float* __restrict__ locs,        // [B, N, 3]
    const float* __restrict__ camera_pose, // [B, 3]
    const float* __restrict__ camera_rot,  // [B, 4]
    const float* __restrict__ depth,       // [B, H, W]
    float* __restrict__ out,               // [B, H, W]
    int N)
{
#pragma clang fp contract(off)
    __shared__ int   s_iy0[BLK];
    __shared__ int   s_jx0[BLK];
    __shared__ float s_z[BLK];
    __shared__ float s_wy[BLK][KSIZE];   // stride 5: gcd(5,32)=1 -> conflict-free
    __shared__ float s_wx[BLK][KSIZE];
    __shared__ int   s_cnt;

    const int b   = blockIdx.y;
    const int n   = blockIdx.x * blockDim.x + threadIdx.x;
    const int tid = threadIdx.x;

    if (tid == 0) s_cnt = 0;

    // --- camera params (uniform within block -> scalarized) ---
    const float qx_raw = camera_rot[b * 4 + 0];
    const float qy_raw = camera_rot[b * 4 + 1];
    const float qz_raw = camera_rot[b * 4 + 2];
    const float qw_raw = camera_rot[b * 4 + 3];
    const float norm2 = ((qx_raw * qx_raw + qy_raw * qy_raw) + qz_raw * qz_raw) + qw_raw * qw_raw;
    const float s = sqrtf(norm2);
    const float qx = -(qx_raw / s);
    const float qy = -(qy_raw / s);
    const float qz = -(qz_raw / s);
    const float qw =  (qw_raw / s);

    const float qx2 = qx * qx, qy2 = qy * qy, qz2 = qz * qz;
    const float qxqy = qx * qy, qxqz = qx * qz, qxqw = qx * qw;
    const float qyqz = qy * qz, qyqw = qy * qw, qzqw = qz * qw;
    const float r00 = (1.0f - 2.0f * qy2) - 2.0f * qz2;
    const float r10 = 2.0f * qxqy - 2.0f * qzqw;
    const float r20 = 2.0f * qxqz + 2.0f * qyqw;
    const float r01 = 2.0f * qxqy + 2.0f * qzqw;
    const float r11 = (1.0f - 2.0f * qx2) - 2.0f * qz2;
    const float r21 = 2.0f * qyqz - 2.0f * qxqw;
    const float r02 = 2.0f * qxqz - 2.0f * qyqw;
    const float r12 = 2.0f * qyqz + 2.0f * qxqw;
    const float r22 = (1.0f - 2.0f * qx2) - 2.0f * qy2;

    const float cpx = camera_pose[b * 3 + 0];
    const float cpy = camera_pose[b * 3 + 1];
    const float cpz = camera_pose[b * 3 + 2];

    // --- projection (guarded loads; no early return before barriers) ---
    bool alive = (n < N);
    float px = 0.0f, py = 0.0f, z = 0.0f;
    if (alive) {
        const float p0 = locs[(size_t)(b * N + n) * 3 + 0] - cpx;
        const float p1 = locs[(size_t)(b * N + n) * 3 + 1] - cpy;
        const float p2 = locs[(size_t)(b * N + n) * 3 + 2] - cpz;

        // p' = p . R, association order matches reference ((a+b)+c)
        const float x = (p0 * r00 + p1 * r10) + p2 * r20;
        const float y = (p0 * r01 + p1 * r11) + p2 * r21;
        z             = (p0 * r02 + p1 * r12) + p2 * r22;

        alive = (z > 0.0f);
        if (alive) {
            px = (x / z) * CAM_FL + (float)CAM_W * 0.5f;
            py = (y / z) * CAM_FL + (float)CAM_H * 0.5f;
            // float-domain frustum cull before any int conversion
            alive = (px >= -(float)RADIUS && px < (float)(CAM_W + RADIUS) &&
                     py >= -(float)RADIUS && py < (float)(CAM_H + RADIUS));
        }
    }

    __syncthreads();   // s_cnt = 0 visible

    // --- block-local compaction: ballot + rank + one LDS atomic per wave ---
    const unsigned long long mask = __ballot(alive);
    const int lane   = tid & 63;
    const int rank   = __popcll(mask & ((1ull << lane) - 1ull));
    const int wcount = __popcll(mask);

    int wbase_v = 0;
    if (lane == 0 && wcount > 0) wbase_v = atomicAdd(&s_cnt, wcount);
    const int wbase = __shfl(wbase_v, 0);

    if (alive) {
        const int i   = wbase + rank;
        const int iy0 = (int)floorf(py);
        const int jx0 = (int)floorf(px);
        s_iy0[i] = iy0;
        s_jx0[i] = jx0;
        s_z[i]   = z;
        // separable Gaussian: 5 row weights + 5 col weights per survivor
#pragma unroll
        for (int k = 0; k < KSIZE; ++k) {
            const float dyf = (float)(iy0 + k - RADIUS) - py;
            const float dxf = (float)(jx0 + k - RADIUS) - px;
            s_wy[i][k] = __expf(-(dyf * dyf) * 0.5f);
            s_wx[i][k] = __expf(-(dxf * dxf) * 0.5f);
        }
    }

    __syncthreads();

    // --- tap-parallel splat over the block's survivors ---
    const int ns    = s_cnt;
    const int total = ns * TAPS;
    const float* depth_b = depth + (size_t)b * (CAM_H * CAM_W);
    float*       out_b   = out   + (size_t)b * (CAM_H * CAM_W);

    for (int t = tid; t < total; t += BLK) {
        const int si  = t / TAPS;            // magic-mul const division
        const int tap = t - si * TAPS;
        const int ti  = tap / KSIZE;
        const int tj  = tap - ti * KSIZE;

        // 25 consecutive lanes share one survivor -> LDS broadcasts
        const int iy = s_iy0[si] + ti - RADIUS;
        const int jx = s_jx0[si] + tj - RADIUS;
        if ((unsigned)iy >= (unsigned)CAM_H || (unsigned)jx >= (unsigned)CAM_W)
            continue;

        const int pix = iy * CAM_W + jx;
        const float d = depth_b[pix];
        if (s_z[si] <= d) {
            const float w = s_wy[si][ti] * s_wx[si][tj];
            atomicAdd(&out_b[pix], w);
        }
    }
}

extern "C" void kernel_launch(void* const* d_in, const int* in_sizes, int n_in,
                              void* d_out, int out_size, void* d_ws, size_t ws_size,
                              hipStream_t stream) {
    const float* locs        = (const float*)d_in[0];
    const float* camera_pose = (const float*)d_in[1];
    const float* camera_rot  = (const float*)d_in[2];
    const float* depth_mask  = (const float*)d_in[3];
    float* out = (float*)d_out;

    const int B = in_sizes[1] / 3;             // camera_pose is [B,3]
    const int N = in_sizes[0] / (3 * B);       // locs is [B,N,3]

    // harness poisons d_out with 0xAA before every timed launch
    hipMemsetAsync(d_out, 0, (size_t)out_size * sizeof(float), stream);

    dim3 block(BLK, 1, 1);
    dim3 grid((N + BLK - 1) / BLK, B, 1);
    particle_project_kernel<<<grid, block, 0, stream>>>(
        locs, camera_pose, camera_rot, depth_mask, out, N);
}